// Round 1
// baseline (19716.196 us; speedup 1.0000x reference)
//
#include <hip/hip_runtime.h>
#include <cstdint>

typedef float vf2 __attribute__((ext_vector_type(2)));

#define GB_M 128
#define GB_N 64
#define GB_K 16

// C[m,n] = act( sum_k A[row(m),k]*B[n,k] + bias[n] )
__global__ __launch_bounds__(256) void gemm_bt_f32(
    const float* __restrict__ A, const float* __restrict__ B,
    const float* __restrict__ bias, float* __restrict__ C,
    int Mc, int N, int K, int tc_shift, int Tfull, int t0, int act)
{
  __shared__ float As[GB_K][GB_M + 4];
  __shared__ float Bs[GB_K][GB_N + 4];
  const int tid = threadIdx.x;
  const int m0 = blockIdx.y * GB_M;
  const int n0 = blockIdx.x * GB_N;
  const int tx = tid & 15;
  const int ty = tid >> 4;

  const int tcmask = (1 << tc_shift) - 1;
  int arow[2];
#pragma unroll
  for (int i = 0; i < 2; i++) {
    int f = tid + i * 256;
    int row = f >> 2;
    int rc = m0 + row;
    arow[i] = (rc >> tc_shift) * Tfull + t0 + (rc & tcmask);
  }
  const int akq = tid & 3;
  const int brow = tid >> 2;
  const int bn = n0 + brow;

  float acc[8][4];
#pragma unroll
  for (int i = 0; i < 8; i++)
#pragma unroll
    for (int j = 0; j < 4; j++) acc[i][j] = 0.f;

  for (int k0 = 0; k0 < K; k0 += GB_K) {
#pragma unroll
    for (int i = 0; i < 2; i++) {
      int f = tid + i * 256;
      int row = f >> 2;
      float4 v = *(const float4*)(A + (size_t)arow[i] * K + k0 + akq * 4);
      As[akq * 4 + 0][row] = v.x; As[akq * 4 + 1][row] = v.y;
      As[akq * 4 + 2][row] = v.z; As[akq * 4 + 3][row] = v.w;
    }
    {
      float4 v = make_float4(0.f, 0.f, 0.f, 0.f);
      if (bn < N) v = *(const float4*)(B + (size_t)bn * K + k0 + akq * 4);
      Bs[akq * 4 + 0][brow] = v.x; Bs[akq * 4 + 1][brow] = v.y;
      Bs[akq * 4 + 2][brow] = v.z; Bs[akq * 4 + 3][brow] = v.w;
    }
    __syncthreads();
#pragma unroll
    for (int k = 0; k < GB_K; k++) {
      float4 a0 = *(const float4*)&As[k][ty * 8];
      float4 a1 = *(const float4*)&As[k][ty * 8 + 4];
      float4 b0 = *(const float4*)&Bs[k][tx * 4];
      float av[8] = {a0.x, a0.y, a0.z, a0.w, a1.x, a1.y, a1.z, a1.w};
      float bv[4] = {b0.x, b0.y, b0.z, b0.w};
#pragma unroll
      for (int i = 0; i < 8; i++)
#pragma unroll
        for (int j = 0; j < 4; j++) acc[i][j] += av[i] * bv[j];
    }
    __syncthreads();
  }

#pragma unroll
  for (int j = 0; j < 4; j++) {
    int n = n0 + tx * 4 + j;
    if (n >= N) continue;
    float bz = bias[n];
#pragma unroll
    for (int i = 0; i < 8; i++) {
      int m = m0 + ty * 8 + i;
      float x = acc[i][j] + bz;
      if (act == 1) {
        x = 1.0507009873554805f * (x > 0.f ? x : 1.6732632423543772f * (__expf(x) - 1.f));
      } else if (act == 2) {
        x = tanhf(x);
      }
      C[(size_t)m * N + n] = x;
    }
  }
}

#define RT 384
#define RNWG 256

// fused-GEMM tile geometry (inside gru_rec): 128x96, K-step 16, 3 tiles/WG
#define FG_M 128
#define FG_N 96
#define FG_K 16

__device__ __forceinline__ void pollge(const unsigned* fp, unsigned want) {
  while (__hip_atomic_load(fp, __ATOMIC_RELAXED, __HIP_MEMORY_SCOPE_AGENT) < want)
    __builtin_amdgcn_s_sleep(1);
}

// Persistent GRU recurrence (round-6 structure, unchanged) + fused next-chunk
// input-projection GEMM time-multiplexed into the poll-idle slots.
// Tc=128; proj double-buffered (ping-pong by chunk parity). GEMM: per WG 3
// tiles of 128x96 (M=4096=32b*128t, N=2304, K=768 in 48 slices of 16).
// Per half-step s: issue slice s+1 global loads (pre-poll, latency hides under
// pollge) -> BAR(s) -> publish flag -> rec compute -> rec h-store -> LDS-write
// slice s+1 (buf (s+1)&1) -> compute slice s (buf s&1). One barrier per phase
// double-buffers the GEMM LDS safely; rec critical path (publish, h-store)
// stays first after the barrier. Summation order identical to gemm_bt_f32
// (k ascending) -> bitwise-identical proj.
__global__ __launch_bounds__(RT, 1) void gru_rec(
    const float* __restrict__ gi, const float* __restrict__ w_hh,
    const float* __restrict__ b_hh, float* __restrict__ hb,
    unsigned* __restrict__ flags, float* __restrict__ seq,
    int t0, int Tc,
    const float* __restrict__ Ag, const float* __restrict__ Wg,
    const float* __restrict__ bgi, float* __restrict__ Cg,
    int t0g, int nt)
{
  __shared__ float hs[8][776];    // rows 0-3: X batches, 4-7: Y batches
  __shared__ __align__(16) float As[2][FG_K][FG_M + 4];
  __shared__ __align__(16) float Bs[2][FG_K][FG_N + 4];
  const int wg = blockIdx.x;
  const int jg = wg & 63;
  const int sd = wg >> 6;
  const int j0 = jg * 12;
  const int tid = threadIdx.x;
  const int p  = tid >> 6;        // wave 0..5
  const int ks = tid & 63;        // lane

  unsigned* flagX_my = flags + (((0 * 4 + sd) * 64) + jg) * 16;
  unsigned* flagY_my = flags + (((1 * 4 + sd) * 64) + jg) * 16;

  // ---- W slice into registers: [g][j2][kk], row g*768+j0+2p+j2, 16B at (kk*64+ks)*4
  float4 wreg[3][2][3];
#pragma unroll
  for (int g = 0; g < 3; g++)
#pragma unroll
    for (int j2 = 0; j2 < 2; j2++)
#pragma unroll
      for (int kk = 0; kk < 3; kk++)
        wreg[g][j2][kk] = *(const float4*)(
            w_hh + (size_t)(g * 768 + j0 + 2 * p + j2) * 768 + (kk * 64 + ks) * 4);

  const int j2l = (ks >> 2) & 1;
  const int cl  = ks & 3;
  const int j_out  = j0 + 2 * p + j2l;
  const int bX_out = 8 * sd + cl;
  const int bY_out = 8 * sd + 4 + cl;
  const float bhr = b_hh[j_out];
  const float bhz = b_hh[768 + j_out];
  const float bhn = b_hh[1536 + j_out];

  // staging: 96 threads per batch-in-half, 8 contiguous floats (4 u64) each
  const int sbi = tid / 96;
  const int sk  = tid - sbi * 96;
  const int jgA = (sk * 8) / 12;
  const int jgB = (sk * 8 + 7) / 12;
  const unsigned* fXA = flags + ((0 * 4 + sd) * 64 + jgA) * 16;
  const unsigned* fXB = flags + ((0 * 4 + sd) * 64 + jgB) * 16;
  const unsigned* fYA = flags + ((1 * 4 + sd) * 64 + jgA) * 16;
  const unsigned* fYB = flags + ((1 * 4 + sd) * 64 + jgB) * 16;

  const bool hi4 = (ks & 4) != 0;
  const bool hi2 = (ks & 2) != 0;
  const bool hi1 = (ks & 1) != 0;

  // ---- fused-GEMM state ----
  const int gty = tid / 24;            // 0..15 (m: gty*8..+7)
  const int gtx = tid - gty * 24;      // 0..23 (n: gtx*4..+3)
  const int tile_base = wg * 3;
  const int total_ph = nt * 48;
  int gph = 0;
  float gacc[8][4];
#pragma unroll
  for (int i = 0; i < 8; i++)
#pragma unroll
    for (int j = 0; j < 4; j++) gacc[i][j] = 0.f;
  float4 sa0 = {}, sa1 = {}, sb0 = {}, sb1 = {}, sb2 = {};

  // issue global loads for phase q into regs (waves 0-3: A, waves 4-5: B)
  auto g_issue = [&](int q) {
    int tl = q / 48;
    int sl = q - tl * 48;
    int ti = tile_base + tl;
    int tm = ti / 24;
    int tn = ti - tm * 24;
    int k0 = sl * FG_K;
    if (tid < 256) {
      // A rows rc = tm*128 + (tid>>2) and +64; global row = tm*1024 + t0g + tt
      int ar0 = tm * 1024 + t0g + (tid >> 2);
      int q4 = (tid & 3) * 4;
      sa0 = *(const float4*)(Ag + (size_t)ar0 * 768 + k0 + q4);
      sa1 = *(const float4*)(Ag + (size_t)(ar0 + 64) * 768 + k0 + q4);
    } else {
      int u = tid - 256;
      int nb = tn * FG_N + (u >> 2);
      int q4 = (u & 3) * 4;
      sb0 = *(const float4*)(Wg + (size_t)nb * 768 + k0 + q4);
      sb1 = *(const float4*)(Wg + (size_t)(nb + 32) * 768 + k0 + q4);
      sb2 = *(const float4*)(Wg + (size_t)(nb + 64) * 768 + k0 + q4);
    }
  };

  // write staged regs into LDS buffer q&1 (transposed to [k][m]/[k][n])
  auto g_write = [&](int q) {
    int b = q & 1;
    if (tid < 256) {
      int r0 = tid >> 2, kq = (tid & 3) * 4;
      As[b][kq + 0][r0] = sa0.x; As[b][kq + 1][r0] = sa0.y;
      As[b][kq + 2][r0] = sa0.z; As[b][kq + 3][r0] = sa0.w;
      int r1 = r0 + 64;
      As[b][kq + 0][r1] = sa1.x; As[b][kq + 1][r1] = sa1.y;
      As[b][kq + 2][r1] = sa1.z; As[b][kq + 3][r1] = sa1.w;
    } else {
      int u = tid - 256;
      int nr = u >> 2, kq = (u & 3) * 4;
      Bs[b][kq + 0][nr] = sb0.x; Bs[b][kq + 1][nr] = sb0.y;
      Bs[b][kq + 2][nr] = sb0.z; Bs[b][kq + 3][nr] = sb0.w;
      Bs[b][kq + 0][nr + 32] = sb1.x; Bs[b][kq + 1][nr + 32] = sb1.y;
      Bs[b][kq + 2][nr + 32] = sb1.z; Bs[b][kq + 3][nr + 32] = sb1.w;
      Bs[b][kq + 0][nr + 64] = sb2.x; Bs[b][kq + 1][nr + 64] = sb2.y;
      Bs[b][kq + 2][nr + 64] = sb2.z; Bs[b][kq + 3][nr + 64] = sb2.w;
    }
  };

  // compute phase q from LDS buffer q&1; epilogue on last slice of a tile
  auto g_compute = [&](int q) {
    int b = q & 1;
#pragma unroll
    for (int k = 0; k < FG_K; k++) {
      float4 a0 = *(const float4*)&As[b][k][gty * 8];
      float4 a1 = *(const float4*)&As[b][k][gty * 8 + 4];
      float4 b0 = *(const float4*)&Bs[b][k][gtx * 4];
      float av[8] = {a0.x, a0.y, a0.z, a0.w, a1.x, a1.y, a1.z, a1.w};
      float bv[4] = {b0.x, b0.y, b0.z, b0.w};
#pragma unroll
      for (int i = 0; i < 8; i++)
#pragma unroll
        for (int j = 0; j < 4; j++) gacc[i][j] += av[i] * bv[j];
    }
    if (q % 48 == 47) {
      int ti = tile_base + q / 48;
      int tm = ti / 24, tn = ti - tm * 24;
      int m = tm * FG_M + gty * 8;
      int n = tn * FG_N + gtx * 4;
      float4 bz = *(const float4*)(bgi + n);
#pragma unroll
      for (int i = 0; i < 8; i++) {
        float4 o = make_float4(gacc[i][0] + bz.x, gacc[i][1] + bz.y,
                               gacc[i][2] + bz.z, gacc[i][3] + bz.w);
        *(float4*)(Cg + (size_t)(m + i) * 2304 + n) = o;
        gacc[i][0] = 0.f; gacc[i][1] = 0.f; gacc[i][2] = 0.f; gacc[i][3] = 0.f;
      }
    }
  };

  // prologue: stage phase 0 (LDS write pre-loop; first BAR1 syncs it)
  if (total_ph > 0) { g_issue(0); g_write(0); }

  for (int tt = 0; tt < Tc; tt++) {
    const int t = t0 + tt;

    // ================= X half =================
    if (gph + 1 < total_ph) g_issue(gph + 1);   // loads fly during pollge
    pollge(fXA, (unsigned)t);
    pollge(fXB, (unsigned)t);
    {
      const unsigned long long* src = (const unsigned long long*)
          (hb + (size_t)(t & 1) * 24576 + (size_t)(8 * sd + sbi) * 768) + sk * 4;
      unsigned long long v[4];
#pragma unroll
      for (int i = 0; i < 4; i++)
        v[i] = __hip_atomic_load(src + i, __ATOMIC_RELAXED, __HIP_MEMORY_SCOPE_AGENT);
      float* dst = &hs[sbi][sk * 8];
      *(float4*)dst = make_float4(
          __uint_as_float((unsigned)v[0]), __uint_as_float((unsigned)(v[0] >> 32)),
          __uint_as_float((unsigned)v[1]), __uint_as_float((unsigned)(v[1] >> 32)));
      *(float4*)(dst + 4) = make_float4(
          __uint_as_float((unsigned)v[2]), __uint_as_float((unsigned)(v[2] >> 32)),
          __uint_as_float((unsigned)v[3]), __uint_as_float((unsigned)(v[3] >> 32)));
    }
    float gXr = 0.f, gXz = 0.f, gXn = 0.f;
    if (ks < 8) {
      const float* gX = gi + ((size_t)bX_out * Tc + tt) * 2304 + j_out;
      gXr = gX[0]; gXz = gX[768]; gXn = gX[1536];
    }
    __syncthreads();   // BAR1: hs X ready; drains outY(t) stores of prev round
    if (tid == 0)
      __hip_atomic_store(flagY_my, (unsigned)t, __ATOMIC_RELAXED, __HIP_MEMORY_SCOPE_AGENT);

    float r3[3];
    {
      vf2 a2[3][2][4];
#pragma unroll
      for (int g = 0; g < 3; g++)
#pragma unroll
        for (int j2 = 0; j2 < 2; j2++)
#pragma unroll
          for (int c = 0; c < 4; c++) a2[g][j2][c] = (vf2)(0.f);
#pragma unroll
      for (int kk = 0; kk < 3; kk++) {
        const int off = (kk * 64 + ks) * 4;
        vf2 hlo[4], hhi[4];
#pragma unroll
        for (int c = 0; c < 4; c++) {
          float4 h = *(const float4*)(&hs[c][0] + off);
          hlo[c] = (vf2){h.x, h.y};
          hhi[c] = (vf2){h.z, h.w};
        }
#pragma unroll
        for (int g = 0; g < 3; g++)
#pragma unroll
          for (int j2 = 0; j2 < 2; j2++) {
            float4 w = wreg[g][j2][kk];
            vf2 wlo = (vf2){w.x, w.y};
            vf2 whi = (vf2){w.z, w.w};
#pragma unroll
            for (int c = 0; c < 4; c++) {
              a2[g][j2][c] = __builtin_elementwise_fma(wlo, hlo[c], a2[g][j2][c]);
              a2[g][j2][c] = __builtin_elementwise_fma(whi, hhi[c], a2[g][j2][c]);
            }
          }
      }
      float acc[3][2][4];
#pragma unroll
      for (int g = 0; g < 3; g++)
#pragma unroll
        for (int j2 = 0; j2 < 2; j2++)
#pragma unroll
          for (int c = 0; c < 4; c++) acc[g][j2][c] = a2[g][j2][c].x + a2[g][j2][c].y;

      float r12[3][4];
#pragma unroll
      for (int g = 0; g < 3; g++)
#pragma unroll
        for (int c = 0; c < 4; c++) {
          float send = hi4 ? acc[g][0][c] : acc[g][1][c];
          float keep = hi4 ? acc[g][1][c] : acc[g][0][c];
          r12[g][c] = keep + __shfl_xor(send, 4);
        }
      float r6[3][2];
#pragma unroll
      for (int g = 0; g < 3; g++)
#pragma unroll
        for (int c2 = 0; c2 < 2; c2++) {
          float send = hi2 ? r12[g][c2] : r12[g][2 + c2];
          float keep = hi2 ? r12[g][2 + c2] : r12[g][c2];
          r6[g][c2] = keep + __shfl_xor(send, 2);
        }
#pragma unroll
      for (int g = 0; g < 3; g++) {
        float send = hi1 ? r6[g][0] : r6[g][1];
        float keep = hi1 ? r6[g][1] : r6[g][0];
        r3[g] = keep + __shfl_xor(send, 1);
      }
#pragma unroll
      for (int g = 0; g < 3; g++) {
        r3[g] += __shfl_xor(r3[g], 8);
        r3[g] += __shfl_xor(r3[g], 16);
        r3[g] += __shfl_xor(r3[g], 32);
      }
    }
    if (ks < 8) {
      float hp = hs[cl][j_out];
      float r = 1.f / (1.f + __expf(-(gXr + r3[0] + bhr)));
      float z = 1.f / (1.f + __expf(-(gXz + r3[1] + bhz)));
      float n = tanhf(gXn + r * (r3[2] + bhn));
      float hv = (1.f - z) * n + z * hp;
      __hip_atomic_store(hb + (size_t)((t + 1) & 1) * 24576 + (size_t)bX_out * 768 + j_out,
                         hv, __ATOMIC_RELAXED, __HIP_MEMORY_SCOPE_AGENT);
      seq[((size_t)bX_out * 1024 + t) * 768 + j_out] = hv;
    }
    // fused GEMM slice (after rec store: off the flag/h critical path)
    if (gph + 1 < total_ph) g_write(gph + 1);
    if (gph < total_ph) g_compute(gph);
    gph++;

    // ================= Y half =================
    if (gph + 1 < total_ph) g_issue(gph + 1);
    pollge(fYA, (unsigned)t);
    pollge(fYB, (unsigned)t);
    {
      const unsigned long long* src = (const unsigned long long*)
          (hb + (size_t)(t & 1) * 24576 + (size_t)(8 * sd + 4 + sbi) * 768) + sk * 4;
      unsigned long long v[4];
#pragma unroll
      for (int i = 0; i < 4; i++)
        v[i] = __hip_atomic_load(src + i, __ATOMIC_RELAXED, __HIP_MEMORY_SCOPE_AGENT);
      float* dst = &hs[4 + sbi][sk * 8];
      *(float4*)dst = make_float4(
          __uint_as_float((unsigned)v[0]), __uint_as_float((unsigned)(v[0] >> 32)),
          __uint_as_float((unsigned)v[1]), __uint_as_float((unsigned)(v[1] >> 32)));
      *(float4*)(dst + 4) = make_float4(
          __uint_as_float((unsigned)v[2]), __uint_as_float((unsigned)(v[2] >> 32)),
          __uint_as_float((unsigned)v[3]), __uint_as_float((unsigned)(v[3] >> 32)));
    }
    float gYr = 0.f, gYz = 0.f, gYn = 0.f;
    if (ks < 8) {
      const float* gY = gi + ((size_t)bY_out * Tc + tt) * 2304 + j_out;
      gYr = gY[0]; gYz = gY[768]; gYn = gY[1536];
    }
    __syncthreads();   // BAR2: hs Y ready; drains outX(t+1) stores
    if (tid == 0)
      __hip_atomic_store(flagX_my, (unsigned)(t + 1), __ATOMIC_RELAXED, __HIP_MEMORY_SCOPE_AGENT);

    {
      vf2 a2[3][2][4];
#pragma unroll
      for (int g = 0; g < 3; g++)
#pragma unroll
        for (int j2 = 0; j2 < 2; j2++)
#pragma unroll
          for (int c = 0; c < 4; c++) a2[g][j2][c] = (vf2)(0.f);
#pragma unroll
      for (int kk = 0; kk < 3; kk++) {
        const int off = (kk * 64 + ks) * 4;
        vf2 hlo[4], hhi[4];
#pragma unroll
        for (int c = 0; c < 4; c++) {
          float4 h = *(const float4*)(&hs[4 + c][0] + off);
          hlo[c] = (vf2){h.x, h.y};
          hhi[c] = (vf2){h.z, h.w};
        }
#pragma unroll
        for (int g = 0; g < 3; g++)
#pragma unroll
          for (int j2 = 0; j2 < 2; j2++) {
            float4 w = wreg[g][j2][kk];
            vf2 wlo = (vf2){w.x, w.y};
            vf2 whi = (vf2){w.z, w.w};
#pragma unroll
            for (int c = 0; c < 4; c++) {
              a2[g][j2][c] = __builtin_elementwise_fma(wlo, hlo[c], a2[g][j2][c]);
              a2[g][j2][c] = __builtin_elementwise_fma(whi, hhi[c], a2[g][j2][c]);
            }
          }
      }
      float acc[3][2][4];
#pragma unroll
      for (int g = 0; g < 3; g++)
#pragma unroll
        for (int j2 = 0; j2 < 2; j2++)
#pragma unroll
          for (int c = 0; c < 4; c++) acc[g][j2][c] = a2[g][j2][c].x + a2[g][j2][c].y;

      float r12[3][4];
#pragma unroll
      for (int g = 0; g < 3; g++)
#pragma unroll
        for (int c = 0; c < 4; c++) {
          float send = hi4 ? acc[g][0][c] : acc[g][1][c];
          float keep = hi4 ? acc[g][1][c] : acc[g][0][c];
          r12[g][c] = keep + __shfl_xor(send, 4);
        }
      float r6[3][2];
#pragma unroll
      for (int g = 0; g < 3; g++)
#pragma unroll
        for (int c2 = 0; c2 < 2; c2++) {
          float send = hi2 ? r12[g][c2] : r12[g][2 + c2];
          float keep = hi2 ? r12[g][2 + c2] : r12[g][c2];
          r6[g][c2] = keep + __shfl_xor(send, 2);
        }
#pragma unroll
      for (int g = 0; g < 3; g++) {
        float send = hi1 ? r6[g][0] : r6[g][1];
        float keep = hi1 ? r6[g][1] : r6[g][0];
        r3[g] = keep + __shfl_xor(send, 1);
      }
#pragma unroll
      for (int g = 0; g < 3; g++) {
        r3[g] += __shfl_xor(r3[g], 8);
        r3[g] += __shfl_xor(r3[g], 16);
        r3[g] += __shfl_xor(r3[g], 32);
      }
    }
    if (ks < 8) {
      float hp = hs[4 + cl][j_out];
      float r = 1.f / (1.f + __expf(-(gYr + r3[0] + bhr)));
      float z = 1.f / (1.f + __expf(-(gYz + r3[1] + bhz)));
      float n = tanhf(gYn + r * (r3[2] + bhn));
      float hv = (1.f - z) * n + z * hp;
      __hip_atomic_store(hb + (size_t)((t + 1) & 1) * 24576 + (size_t)bY_out * 768 + j_out,
                         hv, __ATOMIC_RELAXED, __HIP_MEMORY_SCOPE_AGENT);
      seq[((size_t)bY_out * 1024 + t) * 768 + j_out] = hv;
    }
    if (gph + 1 < total_ph) g_write(gph + 1);
    if (gph < total_ph) g_compute(gph);
    gph++;
  }
  // tail: publish Y's final step so the next dispatch can start
  __syncthreads();
  if (tid == 0)
    __hip_atomic_store(flagY_my, (unsigned)(t0 + Tc), __ATOMIC_RELAXED, __HIP_MEMORY_SCOPE_AGENT);
}

extern "C" void kernel_launch(void* const* d_in, const int* in_sizes, int n_in,
                              void* d_out, int out_size, void* d_ws, size_t ws_size,
                              hipStream_t stream) {
  const float* feat  = (const float*)d_in[0];
  const float* w_ih0 = (const float*)d_in[2];
  const float* w_hh0 = (const float*)d_in[3];
  const float* b_ih0 = (const float*)d_in[4];
  const float* b_hh0 = (const float*)d_in[5];
  const float* w_ih1 = (const float*)d_in[6];
  const float* w_hh1 = (const float*)d_in[7];
  const float* b_ih1 = (const float*)d_in[8];
  const float* b_hh1 = (const float*)d_in[9];
  const float* fc_w  = (const float*)d_in[10];
  const float* fc_b  = (const float*)d_in[11];
  const float* out_w = (const float*)d_in[12];
  const float* out_b = (const float*)d_in[13];
  float* out = (float*)d_out;

  // Tc=128; proj ping-pong (2 x 9,437,184 f = same 18,874,368 f footprint as
  // the old single Tc=256 buffer). Static LDS 54.5 KB + 32 KB dyn = 87.3 KB
  // -> 1 WG/CU (co-residency for the flag protocol).
  const size_t PROJ_CH = (size_t)4096 * 2304;
  const size_t DYN_LDS = 32768;

  float* proj0 = (float*)d_ws;
  float* proj1 = proj0 + PROJ_CH;
  float* seq  = proj0 + 2 * PROJ_CH;                        // 25,165,824 f
  float* hbuf = seq + (size_t)25165824;                     // 2*24576 f
  unsigned* flags = (unsigned*)(hbuf + 2 * 24576);          // 32 KB
  float* projp[2] = { proj0, proj1 };

  // ---- layer 0 ----
  hipMemsetAsync(hbuf, 0, 2 * 24576 * sizeof(float), stream);
  hipMemsetAsync(flags, 0, 32768, stream);
  // standalone proj for chunk 0 only
  gemm_bt_f32<<<dim3(36, 32), dim3(256), 0, stream>>>(
      feat, w_ih0, b_ih0, proj0, 4096, 2304, 768, 7, 1024, 0, 0);
  for (int c = 0; c < 8; c++) {
    const float* Ag; const float* Wg; const float* bg; int t0g;
    if (c < 7) { Ag = feat; Wg = w_ih0; bg = b_ih0; t0g = (c + 1) * 128; }
    else       { Ag = seq;  Wg = w_ih1; bg = b_ih1; t0g = 0; }   // L1 chunk 0
    gru_rec<<<dim3(RNWG), dim3(RT), DYN_LDS, stream>>>(
        projp[c & 1], w_hh0, b_hh0, hbuf, flags, seq, c * 128, 128,
        Ag, Wg, bg, projp[(c + 1) & 1], t0g, 3);
  }
  // ---- layer 1 ----
  hipMemsetAsync(hbuf, 0, 2 * 24576 * sizeof(float), stream);
  hipMemsetAsync(flags, 0, 32768, stream);
  for (int c = 0; c < 8; c++) {
    int nt = (c < 7) ? 3 : 0;
    int t0g = (c + 1) * 128;
    gru_rec<<<dim3(RNWG), dim3(RT), DYN_LDS, stream>>>(
        projp[c & 1], w_hh1, b_hh1, hbuf, flags, seq, c * 128, 128,
        seq, w_ih1, b_ih1, projp[(c + 1) & 1], t0g, nt);
  }
  // ---- fc + SELU ----
  gemm_bt_f32<<<dim3(8, 256), dim3(256), 0, stream>>>(
      seq, fc_w, fc_b, proj0, 32768, 512, 768, 15, 32768, 0, 1);
  // ---- out + tanh ----
  gemm_bt_f32<<<dim3(1, 256), dim3(256), 0, stream>>>(
      proj0, out_w, out_b, out, 32768, 39, 512, 15, 32768, 0, 2);
}

// Round 2
// 14038.820 us; speedup vs baseline: 1.4044x; 1.4044x over previous
//
#include <hip/hip_runtime.h>
#include <cstdint>

typedef float vf2 __attribute__((ext_vector_type(2)));

#define GB_M 128
#define GB_N 64
#define GB_K 16

// C[m,n] = act( sum_k A[row(m),k]*B[n,k] + bias[n] )
// Inner product packed as v_pk_fma_f32: acc2[ip][j] holds rows (2ip,2ip+1),
// col j. Same k-ascending summation order as the scalar version ->
// bitwise-identical results.
__global__ __launch_bounds__(256) void gemm_bt_f32(
    const float* __restrict__ A, const float* __restrict__ B,
    const float* __restrict__ bias, float* __restrict__ C,
    int Mc, int N, int K, int tc_shift, int Tfull, int t0, int act)
{
  __shared__ float As[GB_K][GB_M + 4];
  __shared__ float Bs[GB_K][GB_N + 4];
  const int tid = threadIdx.x;
  const int m0 = blockIdx.y * GB_M;
  const int n0 = blockIdx.x * GB_N;
  const int tx = tid & 15;
  const int ty = tid >> 4;

  const int tcmask = (1 << tc_shift) - 1;
  int arow[2];
#pragma unroll
  for (int i = 0; i < 2; i++) {
    int f = tid + i * 256;
    int row = f >> 2;
    int rc = m0 + row;
    arow[i] = (rc >> tc_shift) * Tfull + t0 + (rc & tcmask);
  }
  const int akq = tid & 3;
  const int brow = tid >> 2;
  const int bn = n0 + brow;

  vf2 acc2[4][4];
#pragma unroll
  for (int i = 0; i < 4; i++)
#pragma unroll
    for (int j = 0; j < 4; j++) acc2[i][j] = (vf2)(0.f);

  for (int k0 = 0; k0 < K; k0 += GB_K) {
#pragma unroll
    for (int i = 0; i < 2; i++) {
      int f = tid + i * 256;
      int row = f >> 2;
      float4 v = *(const float4*)(A + (size_t)arow[i] * K + k0 + akq * 4);
      As[akq * 4 + 0][row] = v.x; As[akq * 4 + 1][row] = v.y;
      As[akq * 4 + 2][row] = v.z; As[akq * 4 + 3][row] = v.w;
    }
    {
      float4 v = make_float4(0.f, 0.f, 0.f, 0.f);
      if (bn < N) v = *(const float4*)(B + (size_t)bn * K + k0 + akq * 4);
      Bs[akq * 4 + 0][brow] = v.x; Bs[akq * 4 + 1][brow] = v.y;
      Bs[akq * 4 + 2][brow] = v.z; Bs[akq * 4 + 3][brow] = v.w;
    }
    __syncthreads();
#pragma unroll
    for (int k = 0; k < GB_K; k++) {
      float4 a0 = *(const float4*)&As[k][ty * 8];
      float4 a1 = *(const float4*)&As[k][ty * 8 + 4];
      float4 b0 = *(const float4*)&Bs[k][tx * 4];
      vf2 a2[4];
      a2[0] = (vf2){a0.x, a0.y}; a2[1] = (vf2){a0.z, a0.w};
      a2[2] = (vf2){a1.x, a1.y}; a2[3] = (vf2){a1.z, a1.w};
      float bv[4] = {b0.x, b0.y, b0.z, b0.w};
#pragma unroll
      for (int j = 0; j < 4; j++) {
        vf2 bs = (vf2){bv[j], bv[j]};
#pragma unroll
        for (int ip = 0; ip < 4; ip++)
          acc2[ip][j] = __builtin_elementwise_fma(a2[ip], bs, acc2[ip][j]);
      }
    }
    __syncthreads();
  }

#pragma unroll
  for (int j = 0; j < 4; j++) {
    int n = n0 + tx * 4 + j;
    if (n >= N) continue;
    float bz = bias[n];
#pragma unroll
    for (int i = 0; i < 8; i++) {
      int m = m0 + ty * 8 + i;
      float x = ((i & 1) ? acc2[i >> 1][j].y : acc2[i >> 1][j].x) + bz;
      if (act == 1) {
        x = 1.0507009873554805f * (x > 0.f ? x : 1.6732632423543772f * (__expf(x) - 1.f));
      } else if (act == 2) {
        x = tanhf(x);
      }
      C[(size_t)m * N + n] = x;
    }
  }
}

#define RT 384
#define RNWG 256

__device__ __forceinline__ void pollge(const unsigned* fp, unsigned want) {
  while (__hip_atomic_load(fp, __ATOMIC_RELAXED, __HIP_MEMORY_SCOPE_AGENT) < want)
    __builtin_amdgcn_s_sleep(1);
}

// Persistent GRU recurrence, round-6: r5's batch-pair stagger + W-in-registers
// + packed fp32 FMA.
// 256 WGs = 4 super-domains (8 batches) x 64 jg (12 hidden cols). Each WG:
// halves X (b 8sd..+3) / Y (8sd+4..+7), staggered; 2 barriers / 2 steps;
// flags publish after the barrier's vmcnt(0) drain (unchanged from r5).
// W: each thread's 6 rows x 12 k-floats (same for X and Y) = 18 float4 in
// VGPRs, loaded coalesced from global once. K-loop reads only h from LDS
// (12 ds_read_b128 per half). Accumulate in float2 (v_pk_fma_f32).
// Dummy 64 KB dynamic LDS keeps allocation >80 KB -> 1 WG/CU (co-residency).
__global__ __launch_bounds__(RT, 1) void gru_rec(
    const float* __restrict__ gi, const float* __restrict__ w_hh,
    const float* __restrict__ b_hh, float* __restrict__ hb,
    unsigned* __restrict__ flags, float* __restrict__ seq,
    int t0, int Tc)
{
  __shared__ float hs[8][776];    // rows 0-3: X batches, 4-7: Y batches
  const int wg = blockIdx.x;
  const int jg = wg & 63;
  const int sd = wg >> 6;
  const int j0 = jg * 12;
  const int tid = threadIdx.x;
  const int p  = tid >> 6;        // wave 0..5
  const int ks = tid & 63;        // lane

  unsigned* flagX_my = flags + (((0 * 4 + sd) * 64) + jg) * 16;
  unsigned* flagY_my = flags + (((1 * 4 + sd) * 64) + jg) * 16;

  // ---- W slice into registers: [g][j2][kk], row g*768+j0+2p+j2, 16B at (kk*64+ks)*4
  float4 wreg[3][2][3];
#pragma unroll
  for (int g = 0; g < 3; g++)
#pragma unroll
    for (int j2 = 0; j2 < 2; j2++)
#pragma unroll
      for (int kk = 0; kk < 3; kk++)
        wreg[g][j2][kk] = *(const float4*)(
            w_hh + (size_t)(g * 768 + j0 + 2 * p + j2) * 768 + (kk * 64 + ks) * 4);

  const int j2l = (ks >> 2) & 1;
  const int cl  = ks & 3;
  const int j_out  = j0 + 2 * p + j2l;
  const int bX_out = 8 * sd + cl;
  const int bY_out = 8 * sd + 4 + cl;
  const float bhr = b_hh[j_out];
  const float bhz = b_hh[768 + j_out];
  const float bhn = b_hh[1536 + j_out];

  // staging: 96 threads per batch-in-half, 8 contiguous floats (4 u64) each
  const int sbi = tid / 96;
  const int sk  = tid - sbi * 96;
  const int jgA = (sk * 8) / 12;
  const int jgB = (sk * 8 + 7) / 12;
  const unsigned* fXA = flags + ((0 * 4 + sd) * 64 + jgA) * 16;
  const unsigned* fXB = flags + ((0 * 4 + sd) * 64 + jgB) * 16;
  const unsigned* fYA = flags + ((1 * 4 + sd) * 64 + jgA) * 16;
  const unsigned* fYB = flags + ((1 * 4 + sd) * 64 + jgB) * 16;

  const bool hi4 = (ks & 4) != 0;
  const bool hi2 = (ks & 2) != 0;
  const bool hi1 = (ks & 1) != 0;

  for (int tt = 0; tt < Tc; tt++) {
    const int t = t0 + tt;

    // ================= X half =================
    pollge(fXA, (unsigned)t);
    pollge(fXB, (unsigned)t);
    {
      const unsigned long long* src = (const unsigned long long*)
          (hb + (size_t)(t & 1) * 24576 + (size_t)(8 * sd + sbi) * 768) + sk * 4;
      unsigned long long v[4];
#pragma unroll
      for (int i = 0; i < 4; i++)
        v[i] = __hip_atomic_load(src + i, __ATOMIC_RELAXED, __HIP_MEMORY_SCOPE_AGENT);
      float* dst = &hs[sbi][sk * 8];
      *(float4*)dst = make_float4(
          __uint_as_float((unsigned)v[0]), __uint_as_float((unsigned)(v[0] >> 32)),
          __uint_as_float((unsigned)v[1]), __uint_as_float((unsigned)(v[1] >> 32)));
      *(float4*)(dst + 4) = make_float4(
          __uint_as_float((unsigned)v[2]), __uint_as_float((unsigned)(v[2] >> 32)),
          __uint_as_float((unsigned)v[3]), __uint_as_float((unsigned)(v[3] >> 32)));
    }
    float gXr = 0.f, gXz = 0.f, gXn = 0.f;
    if (ks < 8) {
      const float* gX = gi + ((size_t)bX_out * Tc + tt) * 2304 + j_out;
      gXr = gX[0]; gXz = gX[768]; gXn = gX[1536];
    }
    __syncthreads();   // BAR1: hs X ready; drains outY(t) stores of prev round
    if (tid == 0)
      __hip_atomic_store(flagY_my, (unsigned)t, __ATOMIC_RELAXED, __HIP_MEMORY_SCOPE_AGENT);

    float r3[3];
    {
      vf2 a2[3][2][4];
#pragma unroll
      for (int g = 0; g < 3; g++)
#pragma unroll
        for (int j2 = 0; j2 < 2; j2++)
#pragma unroll
          for (int c = 0; c < 4; c++) a2[g][j2][c] = (vf2)(0.f);
#pragma unroll
      for (int kk = 0; kk < 3; kk++) {
        const int off = (kk * 64 + ks) * 4;
        vf2 hlo[4], hhi[4];
#pragma unroll
        for (int c = 0; c < 4; c++) {
          float4 h = *(const float4*)(&hs[c][0] + off);
          hlo[c] = (vf2){h.x, h.y};
          hhi[c] = (vf2){h.z, h.w};
        }
#pragma unroll
        for (int g = 0; g < 3; g++)
#pragma unroll
          for (int j2 = 0; j2 < 2; j2++) {
            float4 w = wreg[g][j2][kk];
            vf2 wlo = (vf2){w.x, w.y};
            vf2 whi = (vf2){w.z, w.w};
#pragma unroll
            for (int c = 0; c < 4; c++) {
              a2[g][j2][c] = __builtin_elementwise_fma(wlo, hlo[c], a2[g][j2][c]);
              a2[g][j2][c] = __builtin_elementwise_fma(whi, hhi[c], a2[g][j2][c]);
            }
          }
      }
      float acc[3][2][4];
#pragma unroll
      for (int g = 0; g < 3; g++)
#pragma unroll
        for (int j2 = 0; j2 < 2; j2++)
#pragma unroll
          for (int c = 0; c < 4; c++) acc[g][j2][c] = a2[g][j2][c].x + a2[g][j2][c].y;

      float r12[3][4];
#pragma unroll
      for (int g = 0; g < 3; g++)
#pragma unroll
        for (int c = 0; c < 4; c++) {
          float send = hi4 ? acc[g][0][c] : acc[g][1][c];
          float keep = hi4 ? acc[g][1][c] : acc[g][0][c];
          r12[g][c] = keep + __shfl_xor(send, 4);
        }
      float r6[3][2];
#pragma unroll
      for (int g = 0; g < 3; g++)
#pragma unroll
        for (int c2 = 0; c2 < 2; c2++) {
          float send = hi2 ? r12[g][c2] : r12[g][2 + c2];
          float keep = hi2 ? r12[g][2 + c2] : r12[g][c2];
          r6[g][c2] = keep + __shfl_xor(send, 2);
        }
#pragma unroll
      for (int g = 0; g < 3; g++) {
        float send = hi1 ? r6[g][0] : r6[g][1];
        float keep = hi1 ? r6[g][1] : r6[g][0];
        r3[g] = keep + __shfl_xor(send, 1);
      }
#pragma unroll
      for (int g = 0; g < 3; g++) {
        r3[g] += __shfl_xor(r3[g], 8);
        r3[g] += __shfl_xor(r3[g], 16);
        r3[g] += __shfl_xor(r3[g], 32);
      }
    }
    if (ks < 8) {
      float hp = hs[cl][j_out];
      float r = 1.f / (1.f + __expf(-(gXr + r3[0] + bhr)));
      float z = 1.f / (1.f + __expf(-(gXz + r3[1] + bhz)));
      float n = tanhf(gXn + r * (r3[2] + bhn));
      float hv = (1.f - z) * n + z * hp;
      __hip_atomic_store(hb + (size_t)((t + 1) & 1) * 24576 + (size_t)bX_out * 768 + j_out,
                         hv, __ATOMIC_RELAXED, __HIP_MEMORY_SCOPE_AGENT);
      seq[((size_t)bX_out * 1024 + t) * 768 + j_out] = hv;
    }

    // ================= Y half =================
    pollge(fYA, (unsigned)t);
    pollge(fYB, (unsigned)t);
    {
      const unsigned long long* src = (const unsigned long long*)
          (hb + (size_t)(t & 1) * 24576 + (size_t)(8 * sd + 4 + sbi) * 768) + sk * 4;
      unsigned long long v[4];
#pragma unroll
      for (int i = 0; i < 4; i++)
        v[i] = __hip_atomic_load(src + i, __ATOMIC_RELAXED, __HIP_MEMORY_SCOPE_AGENT);
      float* dst = &hs[4 + sbi][sk * 8];
      *(float4*)dst = make_float4(
          __uint_as_float((unsigned)v[0]), __uint_as_float((unsigned)(v[0] >> 32)),
          __uint_as_float((unsigned)v[1]), __uint_as_float((unsigned)(v[1] >> 32)));
      *(float4*)(dst + 4) = make_float4(
          __uint_as_float((unsigned)v[2]), __uint_as_float((unsigned)(v[2] >> 32)),
          __uint_as_float((unsigned)v[3]), __uint_as_float((unsigned)(v[3] >> 32)));
    }
    float gYr = 0.f, gYz = 0.f, gYn = 0.f;
    if (ks < 8) {
      const float* gY = gi + ((size_t)bY_out * Tc + tt) * 2304 + j_out;
      gYr = gY[0]; gYz = gY[768]; gYn = gY[1536];
    }
    __syncthreads();   // BAR2: hs Y ready; drains outX(t+1) stores
    if (tid == 0)
      __hip_atomic_store(flagX_my, (unsigned)(t + 1), __ATOMIC_RELAXED, __HIP_MEMORY_SCOPE_AGENT);

    {
      vf2 a2[3][2][4];
#pragma unroll
      for (int g = 0; g < 3; g++)
#pragma unroll
        for (int j2 = 0; j2 < 2; j2++)
#pragma unroll
          for (int c = 0; c < 4; c++) a2[g][j2][c] = (vf2)(0.f);
#pragma unroll
      for (int kk = 0; kk < 3; kk++) {
        const int off = (kk * 64 + ks) * 4;
        vf2 hlo[4], hhi[4];
#pragma unroll
        for (int c = 0; c < 4; c++) {
          float4 h = *(const float4*)(&hs[4 + c][0] + off);
          hlo[c] = (vf2){h.x, h.y};
          hhi[c] = (vf2){h.z, h.w};
        }
#pragma unroll
        for (int g = 0; g < 3; g++)
#pragma unroll
          for (int j2 = 0; j2 < 2; j2++) {
            float4 w = wreg[g][j2][kk];
            vf2 wlo = (vf2){w.x, w.y};
            vf2 whi = (vf2){w.z, w.w};
#pragma unroll
            for (int c = 0; c < 4; c++) {
              a2[g][j2][c] = __builtin_elementwise_fma(wlo, hlo[c], a2[g][j2][c]);
              a2[g][j2][c] = __builtin_elementwise_fma(whi, hhi[c], a2[g][j2][c]);
            }
          }
      }
      float acc[3][2][4];
#pragma unroll
      for (int g = 0; g < 3; g++)
#pragma unroll
        for (int j2 = 0; j2 < 2; j2++)
#pragma unroll
          for (int c = 0; c < 4; c++) acc[g][j2][c] = a2[g][j2][c].x + a2[g][j2][c].y;

      float r12[3][4];
#pragma unroll
      for (int g = 0; g < 3; g++)
#pragma unroll
        for (int c = 0; c < 4; c++) {
          float send = hi4 ? acc[g][0][c] : acc[g][1][c];
          float keep = hi4 ? acc[g][1][c] : acc[g][0][c];
          r12[g][c] = keep + __shfl_xor(send, 4);
        }
      float r6[3][2];
#pragma unroll
      for (int g = 0; g < 3; g++)
#pragma unroll
        for (int c2 = 0; c2 < 2; c2++) {
          float send = hi2 ? r12[g][c2] : r12[g][2 + c2];
          float keep = hi2 ? r12[g][2 + c2] : r12[g][c2];
          r6[g][c2] = keep + __shfl_xor(send, 2);
        }
#pragma unroll
      for (int g = 0; g < 3; g++) {
        float send = hi1 ? r6[g][0] : r6[g][1];
        float keep = hi1 ? r6[g][1] : r6[g][0];
        r3[g] = keep + __shfl_xor(send, 1);
      }
#pragma unroll
      for (int g = 0; g < 3; g++) {
        r3[g] += __shfl_xor(r3[g], 8);
        r3[g] += __shfl_xor(r3[g], 16);
        r3[g] += __shfl_xor(r3[g], 32);
      }
    }
    if (ks < 8) {
      float hp = hs[4 + cl][j_out];
      float r = 1.f / (1.f + __expf(-(gYr + r3[0] + bhr)));
      float z = 1.f / (1.f + __expf(-(gYz + r3[1] + bhz)));
      float n = tanhf(gYn + r * (r3[2] + bhn));
      float hv = (1.f - z) * n + z * hp;
      __hip_atomic_store(hb + (size_t)((t + 1) & 1) * 24576 + (size_t)bY_out * 768 + j_out,
                         hv, __ATOMIC_RELAXED, __HIP_MEMORY_SCOPE_AGENT);
      seq[((size_t)bY_out * 1024 + t) * 768 + j_out] = hv;
    }
  }
  // tail: publish Y's final step so the next dispatch can start
  __syncthreads();
  if (tid == 0)
    __hip_atomic_store(flagY_my, (unsigned)(t0 + Tc), __ATOMIC_RELAXED, __HIP_MEMORY_SCOPE_AGENT);
}

extern "C" void kernel_launch(void* const* d_in, const int* in_sizes, int n_in,
                              void* d_out, int out_size, void* d_ws, size_t ws_size,
                              hipStream_t stream) {
  const float* feat  = (const float*)d_in[0];
  const float* w_ih0 = (const float*)d_in[2];
  const float* w_hh0 = (const float*)d_in[3];
  const float* b_ih0 = (const float*)d_in[4];
  const float* b_hh0 = (const float*)d_in[5];
  const float* w_ih1 = (const float*)d_in[6];
  const float* w_hh1 = (const float*)d_in[7];
  const float* b_ih1 = (const float*)d_in[8];
  const float* b_hh1 = (const float*)d_in[9];
  const float* fc_w  = (const float*)d_in[10];
  const float* fc_b  = (const float*)d_in[11];
  const float* out_w = (const float*)d_in[12];
  const float* out_b = (const float*)d_in[13];
  float* out = (float*)d_out;

  const int Tc = 256;
  const int McChunk = 32 * Tc;
  const size_t DYN_LDS = 65536;   // dead dynamic LDS: pins 1 WG/CU (>80 KB total)

  float* proj = (float*)d_ws;                               // 18,874,368 f
  float* seq  = proj + (size_t)32 * Tc * 2304;              // 25,165,824 f
  float* hbuf = seq + (size_t)25165824;                     // 2*24576 f
  unsigned* flags = (unsigned*)(hbuf + 2 * 24576);          // 2 x 256 x 64B = 32 KB

  // ---- layer 0 ----
  hipMemsetAsync(hbuf, 0, 2 * 24576 * sizeof(float), stream);
  hipMemsetAsync(flags, 0, 32768, stream);
  for (int c = 0; c < 4; c++) {
    gemm_bt_f32<<<dim3(36, McChunk / 128), dim3(256), 0, stream>>>(
        feat, w_ih0, b_ih0, proj, McChunk, 2304, 768, 8, 1024, c * Tc, 0);
    gru_rec<<<dim3(RNWG), dim3(RT), DYN_LDS, stream>>>(
        proj, w_hh0, b_hh0, hbuf, flags, seq, c * Tc, Tc);
  }
  // ---- layer 1 ----
  hipMemsetAsync(hbuf, 0, 2 * 24576 * sizeof(float), stream);
  hipMemsetAsync(flags, 0, 32768, stream);
  for (int c = 0; c < 4; c++) {
    gemm_bt_f32<<<dim3(36, McChunk / 128), dim3(256), 0, stream>>>(
        seq, w_ih1, b_ih1, proj, McChunk, 2304, 768, 8, 1024, c * Tc, 0);
    gru_rec<<<dim3(RNWG), dim3(RT), DYN_LDS, stream>>>(
        proj, w_hh1, b_hh1, hbuf, flags, seq, c * Tc, Tc);
  }
  // ---- fc + SELU ----
  gemm_bt_f32<<<dim3(8, 256), dim3(256), 0, stream>>>(
      seq, fc_w, fc_b, proj, 32768, 512, 768, 15, 32768, 0, 1);
  // ---- out + tanh ----
  gemm_bt_f32<<<dim3(1, 256), dim3(256), 0, stream>>>(
      proj, out_w, out_b, out, 32768, 39, 512, 15, 32768, 0, 2);
}